// Round 2
// baseline (79.759 us; speedup 1.0000x reference)
//
#include <hip/hip_runtime.h>

// DistanceTransform closed form (verified absmax=0.0 in round 1):
//   d(p)  = Chebyshev (L_inf) distance to nearest seed (replicate-pad => clamp)
//   out(p)= 0 if d==0 else (d-1) - 0.35*log(a*w1 + b*w2)
// where a/b = # edge/corner conv taps whose CLAMPED source pixel has d < d(p),
// w1 = exp(-1/0.35), w2 = exp(-sqrt(2)/0.35).
//
// Round-2 insight: seeds are ~0.1% sparse (~66/image), so
//   d(p) = min over seeds s of max(|py-sy|, |px-sx|)
// computed brute-force per pixel. Single fused kernel:
//   phase 1: block scans its image -> seed list in LDS
//   phase 2: per-thread Chebyshev min over seeds for a 34x34 halo'd region
//   phase 3: epilogue (neighbor counts + log) from LDS, write output.

#define TILE    32
#define REG     34              // TILE + 2 halo
#define REG_SZ  (REG * REG)     // 1156
#define K_ACC   5               // ceil(1156 / 256)
#define SEED_CAP 6144           // ~100x margin over expected ~66 seeds/image

__global__ __launch_bounds__(256) void k_fused(const float* __restrict__ img,
                                               float* __restrict__ out) {
    __shared__ unsigned short slist[SEED_CAP];
    __shared__ int scount;
    __shared__ unsigned char sd[REG_SZ + 4];

    const int t    = threadIdx.x;
    const int b    = blockIdx.x;       // 0..127
    const int n    = b >> 6;           // image 0/1
    const int tile = b & 63;           // 8x8 tiles of 32x32
    const int y0   = (tile >> 3) * TILE;
    const int x0   = (tile & 7) * TILE;

    if (t == 0) scount = 0;
    __syncthreads();

    // ---- Phase 1: scan own image for nonzero seeds ----
    const float4* im4 = reinterpret_cast<const float4*>(img + (n << 16));
    for (int it = 0; it < 64; ++it) {
        const int v = (it << 8) + t;          // float4 index 0..16383
        const float4 val = im4[v];
        const bool n0 = val.x != 0.0f, n1 = val.y != 0.0f,
                   n2 = val.z != 0.0f, n3 = val.w != 0.0f;
        if (n0 | n1 | n2 | n3) {              // rare (~0.4% of iterations per lane group)
            const int base = v << 2;          // flat pixel index = y*256 + x
            if (n0) { int i_ = atomicAdd(&scount, 1); if (i_ < SEED_CAP) slist[i_] = (unsigned short)(base    ); }
            if (n1) { int i_ = atomicAdd(&scount, 1); if (i_ < SEED_CAP) slist[i_] = (unsigned short)(base + 1); }
            if (n2) { int i_ = atomicAdd(&scount, 1); if (i_ < SEED_CAP) slist[i_] = (unsigned short)(base + 2); }
            if (n3) { int i_ = atomicAdd(&scount, 1); if (i_ < SEED_CAP) slist[i_] = (unsigned short)(base + 3); }
        }
    }
    __syncthreads();
    const int cnt = min(scount, SEED_CAP);

    // ---- Phase 2: Chebyshev distance for the 34x34 region (clamped coords) ----
    int gy[K_ACC], gx[K_ACC], best[K_ACC];
    #pragma unroll
    for (int k = 0; k < K_ACC; ++k) {
        const int ri = t + (k << 8);
        const int rr = (ri < REG_SZ) ? ri : 0;     // dummy for inactive slot
        const int ry = rr / REG;
        const int rx = rr - ry * REG;
        gy[k] = min(max(y0 - 1 + ry, 0), 255);     // replicate-pad clamp
        gx[k] = min(max(x0 - 1 + rx, 0), 255);
        best[k] = 1023;
    }
    for (int s = 0; s < cnt; ++s) {
        const int sp = slist[s];                   // broadcast read (same addr)
        const int sy = sp >> 8;
        const int sx = sp & 255;
        #pragma unroll
        for (int k = 0; k < K_ACC; ++k) {
            const int dy = gy[k] - sy;
            const int dx = gx[k] - sx;
            const int ady = (dy < 0) ? -dy : dy;
            const int adx = (dx < 0) ? -dx : dx;
            best[k] = min(best[k], max(ady, adx));
        }
    }
    #pragma unroll
    for (int k = 0; k < K_ACC; ++k) {
        const int ri = t + (k << 8);
        if (ri < REG_SZ) sd[ri] = (unsigned char)best[k];   // d <= 255 always
    }
    __syncthreads();

    // ---- Phase 3: epilogue for the 32x32 output tile ----
    const float W1 = expf(-(1.0f / 0.35f));          // edge tap weight
    const float W2 = expf(-(1.41421356f / 0.35f));   // corner tap weight
    #pragma unroll
    for (int j = 0; j < 4; ++j) {
        const int pi = t + (j << 8);                 // 0..1023 within tile
        const int ly = pi >> 5;
        const int lx = pi & 31;
        const int rc = (ly + 1) * REG + (lx + 1);    // region center
        const int dp = sd[rc];
        // region halo rows/cols already hold clamped-coordinate d-values,
        // so plain +-1 indexing reproduces replicate-pad tap semantics.
        const int a =
            (sd[rc - REG] < dp) + (sd[rc + REG] < dp) +
            (sd[rc - 1  ] < dp) + (sd[rc + 1  ] < dp);
        const int c =
            (sd[rc - REG - 1] < dp) + (sd[rc - REG + 1] < dp) +
            (sd[rc + REG - 1] < dp) + (sd[rc + REG + 1] < dp);
        const float S = (float)a * W1 + (float)c * W2;   // > 0 whenever dp > 0
        const float v = (float)(dp - 1) - 0.35f * logf(S);
        out[(n << 16) + ((y0 + ly) << 8) + (x0 + lx)] = (dp > 0) ? v : 0.0f;
    }
}

extern "C" void kernel_launch(void* const* d_in, const int* in_sizes, int n_in,
                              void* d_out, int out_size, void* d_ws, size_t ws_size,
                              hipStream_t stream) {
    const float* img = (const float*)d_in[0];
    float* out = (float*)d_out;
    k_fused<<<128, 256, 0, stream>>>(img, out);
}

// Round 3
// 62.002 us; speedup vs baseline: 1.2864x; 1.2864x over previous
//
#include <hip/hip_runtime.h>

// DistanceTransform closed form (verified absmax=0.0 in rounds 1-2):
//   d(p)  = Chebyshev (L_inf) distance to nearest seed (replicate-pad => clamp)
//   out(p)= 0 if d==0 else (d-1) - 0.35*log(a*w1 + c*w2)
// where a/c = # edge/corner 3x3 taps whose CLAMPED source pixel has d < d(p),
// w1 = exp(-1/0.35), w2 = exp(-sqrt(2)/0.35).
//
// Round-3 structure (round 2 regressed: every block re-scanned the full image):
//   k_seed: one pass over input -> 8 KB/image seed BITMAP in ws (full overwrite,
//           so the 0xAA-poisoned ws needs no init, no counters, no atomics)
//   k_main: per 16x16 tile: read bitmap (8 words/thread) -> LDS seed list,
//           brute-force Chebyshev over 18x18 halo'd region, fused epilogue.

#define TS      16
#define RG      18              // TS + 2 halo
#define RGSZ    (RG * RG)       // 324
#define SEED_CAP 2048

// ---- Kernel 1: build seed bitmap (1 bit per pixel, 2048 uint32 per image) ----
__global__ __launch_bounds__(256) void k_seed(const float* __restrict__ img,
                                              unsigned short* __restrict__ bm) {
    const int g = blockIdx.x * 256 + threadIdx.x;   // 0..8191
    const int n = g >> 12;                          // image
    const int h = g & 4095;                         // 16-pixel group
    const float4* p = reinterpret_cast<const float4*>(img + (n << 16) + (h << 4));
    unsigned int m = 0;
    #pragma unroll
    for (int q = 0; q < 4; ++q) {
        const float4 v = p[q];
        m |= (unsigned int)(v.x != 0.0f) << (q * 4 + 0);
        m |= (unsigned int)(v.y != 0.0f) << (q * 4 + 1);
        m |= (unsigned int)(v.z != 0.0f) << (q * 4 + 2);
        m |= (unsigned int)(v.w != 0.0f) << (q * 4 + 3);
    }
    bm[g] = (unsigned short)m;                      // full overwrite of ws region
}

// ---- Kernel 2: extract seeds, Chebyshev DT per tile, epilogue ----
__global__ __launch_bounds__(256) void k_main(const unsigned int* __restrict__ bm,
                                              float* __restrict__ out) {
    __shared__ unsigned short slist[SEED_CAP];
    __shared__ int scount;
    __shared__ unsigned char sd[RGSZ + 4];

    const int t    = threadIdx.x;
    const int b    = blockIdx.x;        // 0..511
    const int n    = b >> 8;            // image
    const int tile = b & 255;           // 16x16 grid of 16x16 tiles
    const int y0   = (tile >> 4) * TS;
    const int x0   = (tile & 15) * TS;

    if (t == 0) scount = 0;
    __syncthreads();

    // Phase 1: bitmap (2048 words = 8 KB, L1/L2-resident) -> LDS seed list
    const unsigned int* w = bm + (n << 11);
    #pragma unroll
    for (int k = 0; k < 8; ++k) {
        const int wi = t + (k << 8);
        unsigned int m = w[wi];                 // coalesced
        while (m) {                              // ~66 set bits per image total
            const int bit = __ffs(m) - 1;
            m &= m - 1;
            const int i_ = atomicAdd(&scount, 1);
            if (i_ < SEED_CAP) slist[i_] = (unsigned short)((wi << 5) + bit);
        }
    }
    __syncthreads();
    const int cnt = min(scount, SEED_CAP);

    // Phase 2: Chebyshev distance for the 18x18 region (clamped coords =>
    // replicate-pad semantics). 2 accumulators per thread cover 324 cells.
    int gy0_, gx0_, gy1_, gx1_, best0, best1;
    {
        const int r0 = t;                        // 0..255  (< 324 always)
        const int ry0 = r0 / RG, rx0 = r0 - ry0 * RG;
        gy0_ = min(max(y0 - 1 + ry0, 0), 255);
        gx0_ = min(max(x0 - 1 + rx0, 0), 255);
        const int r1 = t + 256;
        const int rr = (r1 < RGSZ) ? r1 : 0;
        const int ry1 = rr / RG, rx1 = rr - ry1 * RG;
        gy1_ = min(max(y0 - 1 + ry1, 0), 255);
        gx1_ = min(max(x0 - 1 + rx1, 0), 255);
        best0 = 1023; best1 = 1023;
    }
    for (int s = 0; s < cnt; ++s) {
        const int sp = slist[s];                 // broadcast (same address)
        const int sy = sp >> 8;
        const int sx = sp & 255;
        int dy = gy0_ - sy; dy = (dy < 0) ? -dy : dy;
        int dx = gx0_ - sx; dx = (dx < 0) ? -dx : dx;
        best0 = min(best0, max(dy, dx));
        dy = gy1_ - sy; dy = (dy < 0) ? -dy : dy;
        dx = gx1_ - sx; dx = (dx < 0) ? -dx : dx;
        best1 = min(best1, max(dy, dx));
    }
    sd[t] = (unsigned char)best0;
    if (t + 256 < RGSZ) sd[t + 256] = (unsigned char)best1;
    __syncthreads();

    // Phase 3: epilogue, one output pixel per thread (identical math to R1/R2)
    const float W1 = expf(-(1.0f / 0.35f));
    const float W2 = expf(-(1.41421356f / 0.35f));
    const int ly = t >> 4;
    const int lx = t & 15;
    const int rc = (ly + 1) * RG + (lx + 1);
    const int dp = sd[rc];
    const int a =
        (sd[rc - RG] < dp) + (sd[rc + RG] < dp) +
        (sd[rc - 1 ] < dp) + (sd[rc + 1 ] < dp);
    const int c =
        (sd[rc - RG - 1] < dp) + (sd[rc - RG + 1] < dp) +
        (sd[rc + RG - 1] < dp) + (sd[rc + RG + 1] < dp);
    const float S = (float)a * W1 + (float)c * W2;   // > 0 whenever dp > 0
    const float v = (float)(dp - 1) - 0.35f * logf(S);
    out[(n << 16) + ((y0 + ly) << 8) + (x0 + lx)] = (dp > 0) ? v : 0.0f;
}

extern "C" void kernel_launch(void* const* d_in, const int* in_sizes, int n_in,
                              void* d_out, int out_size, void* d_ws, size_t ws_size,
                              hipStream_t stream) {
    const float* img = (const float*)d_in[0];
    float* out = (float*)d_out;
    unsigned short* bm16 = (unsigned short*)d_ws;       // 16 KB bitmap (2 images)
    const unsigned int* bm32 = (const unsigned int*)d_ws;
    k_seed<<<32, 256, 0, stream>>>(img, bm16);
    k_main<<<512, 256, 0, stream>>>(bm32, out);
}